// Round 2
// 6876.059 us; speedup vs baseline: 1.6238x; 1.6238x over previous
//
#include <hip/hip_runtime.h>
#include <hip/hip_bf16.h>
#include <math.h>

#define HDIM 1024
#define NHEAD 16
#define HEADD 64
#define FFDIM 4096
#define NLAYERS 4
#define VOCAB 32000
#define NBATCH 2
#define SEQLEN 1024
#define NTOK (NBATCH * SEQLEN)

// h[tok,d] = emb[x[tok],d] + pe(batch(tok), d)   -- pe indexed by BATCH (faithful quirk)
__global__ void embed_kernel(const int* __restrict__ x, const float* __restrict__ emb,
                             float* __restrict__ h) {
  const int tok = blockIdx.x;
  const int b = tok >> 10;  // SEQLEN = 1024
  const int row = x[tok];
  const float c = -9.210340371976184f / (float)HDIM;  // -ln(10000)/H
#pragma unroll
  for (int i = 0; i < 4; i++) {
    const int d = threadIdx.x + (i << 8);
    const float ang = (float)b * expf(c * (float)(d & ~1));
    const float pe = (d & 1) ? cosf(ang) : sinf(ang);
    h[(size_t)tok * HDIM + d] = emb[(size_t)row * HDIM + d] + pe;
  }
}

// C[M,N] = A[M,K] * W[K,N] + bias[N]; optional ReLU. All fp32.
// 64x64 tile, 256 threads, 4x4 per thread, K-chunk 16. LDS stored [k][m]/[k][n]
// (pad 68 -> 272B row stride keeps float4 LDS reads 16B-aligned => ds_read_b128).
template <bool RELU>
__global__ void gemm_kernel(const float* __restrict__ A, const float* __restrict__ W,
                            const float* __restrict__ bias, float* __restrict__ C,
                            const int M, const int N, const int K) {
  __shared__ float As[16][68];  // [k][m]
  __shared__ float Ws[16][68];  // [k][n]
  const int t = threadIdx.x;
  const int bn = blockIdx.x, bm = blockIdx.y;
  const int tn = t & 15, tm = t >> 4;
  const int lrow = t >> 2, lk0 = (t & 3) << 2;  // A-tile load: row 0..63, 4 consecutive k
  const int wk = t >> 4, wn0 = (t & 15) << 2;   // W-tile load: k 0..15, 4 consecutive n
  float acc[4][4];
#pragma unroll
  for (int i = 0; i < 4; i++)
#pragma unroll
    for (int j = 0; j < 4; j++) acc[i][j] = 0.f;

  const float* Arow = A + (size_t)(bm * 64 + lrow) * K + lk0;
  const float* Wrow = W + (size_t)wk * N + bn * 64 + wn0;

  for (int kk = 0; kk < K; kk += 16) {
    const float4 av = *(const float4*)(Arow + kk);
    As[lk0 + 0][lrow] = av.x;
    As[lk0 + 1][lrow] = av.y;
    As[lk0 + 2][lrow] = av.z;
    As[lk0 + 3][lrow] = av.w;
    *(float4*)&Ws[wk][wn0] = *(const float4*)(Wrow + (size_t)kk * N);
    __syncthreads();
#pragma unroll
    for (int k = 0; k < 16; k++) {
      const float4 a = *(const float4*)&As[k][tm << 2];
      const float4 w = *(const float4*)&Ws[k][tn << 2];
      acc[0][0] += a.x * w.x; acc[0][1] += a.x * w.y; acc[0][2] += a.x * w.z; acc[0][3] += a.x * w.w;
      acc[1][0] += a.y * w.x; acc[1][1] += a.y * w.y; acc[1][2] += a.y * w.z; acc[1][3] += a.y * w.w;
      acc[2][0] += a.z * w.x; acc[2][1] += a.z * w.y; acc[2][2] += a.z * w.z; acc[2][3] += a.z * w.w;
      acc[3][0] += a.w * w.x; acc[3][1] += a.w * w.y; acc[3][2] += a.w * w.z; acc[3][3] += a.w * w.w;
    }
    __syncthreads();
  }

  float bb[4];
#pragma unroll
  for (int j = 0; j < 4; j++) bb[j] = bias[bn * 64 + (tn << 2) + j];
  const size_t cbase = (size_t)(bm * 64 + (tm << 2)) * N + bn * 64 + (tn << 2);
#pragma unroll
  for (int i = 0; i < 4; i++) {
#pragma unroll
    for (int j = 0; j < 4; j++) {
      float v = acc[i][j] + bb[j];
      if (RELU) v = fmaxf(v, 0.f);
      C[cbase + (size_t)i * N + j] = v;
    }
  }
}

// Two-pass LDS-staged attention. One block per (b, head, 8 query rows), 256 threads.
// Phase A: stage K in 64x64 tiles (coalesced float4 -> LDS, pad 65 so the
//          column-pattern score reads are 2 lanes/bank = conflict-free),
//          each thread computes scores for 2 q-rows x 1 k-col per tile.
// Phase B: exact max-subtracted softmax, one wave per 2 rows, shuffle reduce.
// Phase C: stage V tiles into the same buffer; thread owns (q-row, 2 d) output
//          accumulators; sc[] probabilities broadcast within 32-lane groups.
// LDS ~51.5KB -> 3 blocks/CU. K,V each read exactly once per block.
__global__ void attn_kernel(const float* __restrict__ q, const float* __restrict__ k,
                            const float* __restrict__ v, float* __restrict__ o) {
  const int qb = blockIdx.x, nh = blockIdx.y, b = blockIdx.z;
  const int t = threadIdx.x;
  __shared__ float qs[8][HEADD];
  __shared__ float sc[8][SEQLEN];   // 32 KB: full score rows (exact 2-pass softmax)
  __shared__ float kv[64][65];      // staged K or V tile, +1 pad => bank-friendly
  __shared__ float sinv[8];
  const size_t bbase = (size_t)b * SEQLEN * HDIM + (size_t)nh * HEADD;
  const float* kb = k + bbase;
  const float* vb = v + bbase;
  const int srow = t >> 4;          // stage: base row 0..15
  const int scol = (t & 15) << 2;   // stage: float4 col offset 0..60

  for (int idx = t; idx < 8 * HEADD; idx += 256) {
    const int qq = idx >> 6, d = idx & 63;
    qs[qq][d] = q[bbase + (size_t)(qb * 8 + qq) * HDIM + d];
  }

  // ---- Phase A: scores ----
  const int kk = t & 63, qp = t >> 6;  // thread -> k-col, q-row pair {qp, qp+4}
  for (int kt = 0; kt < 16; kt++) {
    __syncthreads();  // prev tile's reads done (first iter: q-stage done)
#pragma unroll
    for (int i = 0; i < 4; i++) {
      const int r = srow + (i << 4);
      const float4 t4 = *(const float4*)(kb + (size_t)((kt << 6) + r) * HDIM + scol);
      kv[r][scol] = t4.x; kv[r][scol + 1] = t4.y;
      kv[r][scol + 2] = t4.z; kv[r][scol + 3] = t4.w;
    }
    __syncthreads();
    float s0 = 0.f, s1 = 0.f;
#pragma unroll
    for (int d = 0; d < HEADD; d++) {
      const float kvv = kv[kk][d];           // (kk+d)%32 banks: 2-way, free
      s0 += qs[qp][d] * kvv;                 // broadcast (wave-uniform addr)
      s1 += qs[qp + 4][d] * kvv;
    }
    sc[qp][(kt << 6) + kk] = s0 * 0.125f;    // 1/sqrt(64)
    sc[qp + 4][(kt << 6) + kk] = s1 * 0.125f;
  }
  __syncthreads();

  // ---- Phase B: softmax (wave w owns rows w and w+4) ----
  const int w = t >> 6, l = t & 63;
#pragma unroll
  for (int rr = 0; rr < 2; rr++) {
    const int r = w + (rr << 2);
    float m = -1e30f;
#pragma unroll
    for (int i = 0; i < 16; i++) m = fmaxf(m, sc[r][l + (i << 6)]);
#pragma unroll
    for (int off = 32; off > 0; off >>= 1) m = fmaxf(m, __shfl_xor(m, off));
    float s = 0.f;
#pragma unroll
    for (int i = 0; i < 16; i++) {
      const float e = __expf(sc[r][l + (i << 6)] - m);
      sc[r][l + (i << 6)] = e;
      s += e;
    }
#pragma unroll
    for (int off = 32; off > 0; off >>= 1) s += __shfl_xor(s, off);
    if (l == 0) sinv[r] = 1.f / s;
  }

  // ---- Phase C: o = P @ V ----
  const int d0 = (t & 31) << 1, qq = t >> 5;  // thread -> (q-row, d pair)
  float o0 = 0.f, o1 = 0.f;
  for (int kt = 0; kt < 16; kt++) {
    __syncthreads();  // softmax done / prev tile reads done
#pragma unroll
    for (int i = 0; i < 4; i++) {
      const int r = srow + (i << 4);
      const float4 t4 = *(const float4*)(vb + (size_t)((kt << 6) + r) * HDIM + scol);
      kv[r][scol] = t4.x; kv[r][scol + 1] = t4.y;
      kv[r][scol + 2] = t4.z; kv[r][scol + 3] = t4.w;
    }
    __syncthreads();
#pragma unroll
    for (int j = 0; j < 64; j++) {
      const float p = sc[qq][(kt << 6) + j];  // broadcast within 32-lane group
      o0 += p * kv[j][d0];                    // 16 banks x2 + upper-half broadcast
      o1 += p * kv[j][d0 + 1];
    }
  }
  const float inv = sinv[qq];
  const size_t obase = bbase + (size_t)(qb * 8 + qq) * HDIM + d0;
  o[obase] = o0 * inv;
  o[obase + 1] = o1 * inv;
}

// h = LayerNorm(h + t_in) * g + b   (one block per token, H=1024, 4 elems/thread)
__global__ void ln_kernel(float* __restrict__ h, const float* __restrict__ t_in,
                          const float* __restrict__ g, const float* __restrict__ bta) {
  const int tok = blockIdx.x;
  const int t = threadIdx.x;
  __shared__ float red[8];
  float r[4];
  float s = 0.f;
  const size_t base = (size_t)tok * HDIM;
#pragma unroll
  for (int i = 0; i < 4; i++) {
    const int d = t + (i << 8);
    r[i] = h[base + d] + t_in[base + d];
    s += r[i];
  }
#pragma unroll
  for (int off = 32; off > 0; off >>= 1) s += __shfl_xor(s, off);
  if ((t & 63) == 0) red[t >> 6] = s;
  __syncthreads();
  const float mean = (red[0] + red[1] + red[2] + red[3]) * (1.f / HDIM);
  float vs = 0.f;
#pragma unroll
  for (int i = 0; i < 4; i++) {
    const float dv = r[i] - mean;
    vs += dv * dv;
  }
#pragma unroll
  for (int off = 32; off > 0; off >>= 1) vs += __shfl_xor(vs, off);
  if ((t & 63) == 0) red[4 + (t >> 6)] = vs;
  __syncthreads();
  const float var = (red[4] + red[5] + red[6] + red[7]) * (1.f / HDIM);
  const float inv = 1.f / sqrtf(var + 1e-5f);
#pragma unroll
  for (int i = 0; i < 4; i++) {
    const int d = t + (i << 8);
    h[base + d] = (r[i] - mean) * inv * g[d] + bta[d];
  }
}

extern "C" void kernel_launch(void* const* d_in, const int* in_sizes, int n_in,
                              void* d_out, int out_size, void* d_ws, size_t ws_size,
                              hipStream_t stream) {
  const int* x = (const int*)d_in[0];
  const float* emb = (const float*)d_in[1];
  const float* Wq = (const float*)d_in[2];
  const float* bq = (const float*)d_in[3];
  const float* Wk = (const float*)d_in[4];
  const float* bk = (const float*)d_in[5];
  const float* Wv = (const float*)d_in[6];
  const float* bv = (const float*)d_in[7];
  const float* Wo = (const float*)d_in[8];
  const float* bo = (const float*)d_in[9];
  const float* ln1g = (const float*)d_in[10];
  const float* ln1b = (const float*)d_in[11];
  const float* W1 = (const float*)d_in[12];
  const float* b1 = (const float*)d_in[13];
  const float* W2 = (const float*)d_in[14];
  const float* b2 = (const float*)d_in[15];
  const float* ln2g = (const float*)d_in[16];
  const float* ln2b = (const float*)d_in[17];
  const float* fcw = (const float*)d_in[18];
  const float* fcb = (const float*)d_in[19];

  float* h = (float*)d_ws;
  const size_t TH = (size_t)NTOK * HDIM;  // 2M floats
  float* qb = h + TH;
  float* kb = qb + TH;
  float* vb = kb + TH;
  float* ob = vb + TH;
  float* tb = ob + TH;
  float* ffb = tb + TH;  // NTOK * FFDIM floats

  embed_kernel<<<NTOK, 256, 0, stream>>>(x, emb, h);

  const dim3 gHH(HDIM / 64, NTOK / 64);
  const dim3 gHF(FFDIM / 64, NTOK / 64);
  const dim3 gHV(VOCAB / 64, NTOK / 64);
  for (int l = 0; l < NLAYERS; l++) {
    const size_t wHH = (size_t)l * HDIM * HDIM;
    gemm_kernel<false><<<gHH, 256, 0, stream>>>(h, Wq + wHH, bq + l * HDIM, qb, NTOK, HDIM, HDIM);
    gemm_kernel<false><<<gHH, 256, 0, stream>>>(h, Wk + wHH, bk + l * HDIM, kb, NTOK, HDIM, HDIM);
    gemm_kernel<false><<<gHH, 256, 0, stream>>>(h, Wv + wHH, bv + l * HDIM, vb, NTOK, HDIM, HDIM);
    attn_kernel<<<dim3(SEQLEN / 8, NHEAD, NBATCH), 256, 0, stream>>>(qb, kb, vb, ob);
    gemm_kernel<false><<<gHH, 256, 0, stream>>>(ob, Wo + wHH, bo + l * HDIM, tb, NTOK, HDIM, HDIM);
    ln_kernel<<<NTOK, 256, 0, stream>>>(h, tb, ln1g + l * HDIM, ln1b + l * HDIM);
    gemm_kernel<true><<<gHF, 256, 0, stream>>>(h, W1 + (size_t)l * HDIM * FFDIM, b1 + l * FFDIM,
                                               ffb, NTOK, FFDIM, HDIM);
    gemm_kernel<false><<<gHH, 256, 0, stream>>>(ffb, W2 + (size_t)l * FFDIM * HDIM, b2 + l * HDIM,
                                                tb, NTOK, HDIM, FFDIM);
    ln_kernel<<<NTOK, 256, 0, stream>>>(h, tb, ln2g + l * HDIM, ln2b + l * HDIM);
  }
  gemm_kernel<false><<<gHV, 256, 0, stream>>>(h, fcw, fcb, (float*)d_out, NTOK, VOCAB, HDIM);
}

// Round 7
// 5382.755 us; speedup vs baseline: 2.0742x; 1.2774x over previous
//
#include <hip/hip_runtime.h>
#include <hip/hip_bf16.h>
#include <math.h>

#define HDIM 1024
#define NHEAD 16
#define HEADD 64
#define FFDIM 4096
#define NLAYERS 4
#define VOCAB 32000
#define NBATCH 2
#define SEQLEN 1024
#define NTOK (NBATCH * SEQLEN)

typedef __attribute__((ext_vector_type(8))) _Float16 f16x8;
typedef __attribute__((ext_vector_type(4))) _Float16 f16x4;
typedef __attribute__((ext_vector_type(4))) float f32x4;

// h[tok,d] = emb[x[tok],d] + pe(batch(tok), d)   -- pe indexed by BATCH (faithful quirk)
__global__ void embed_kernel(const int* __restrict__ x, const float* __restrict__ emb,
                             float* __restrict__ h) {
  const int tok = blockIdx.x;
  const int b = tok >> 10;  // SEQLEN = 1024
  const int row = x[tok];
  const float c = -9.210340371976184f / (float)HDIM;  // -ln(10000)/H
#pragma unroll
  for (int i = 0; i < 4; i++) {
    const int d = threadIdx.x + (i << 8);
    const float ang = (float)b * expf(c * (float)(d & ~1));
    const float pe = (d & 1) ? cosf(ang) : sinf(ang);
    h[(size_t)tok * HDIM + d] = emb[(size_t)row * HDIM + d] + pe;
  }
}

// MFMA GEMM, fp32-in/fp32-out via f16 hi/lo split (3-term: HH + LH + HL).
// C[M,N] = A[M,K] @ W[K,N] + bias[N], optional ReLU.
// 128x128 tile, BK=32, 256 threads = 4 waves in 2x2, each wave 64x64 out
// (4x4 frags of mfma_f32_16x16x32_f16). LDS f16 tiles [128][40] (80B rows:
// 16B-aligned for ds_read_b128; frag reads cover all 32 banks at 2-way).
// M,N,K must be multiples of 128,128,32 (true for all GEMMs here).
template <bool RELU>
__global__ __launch_bounds__(256, 2) void gemm_mfma(
    const float* __restrict__ A, const float* __restrict__ W,
    const float* __restrict__ bias, float* __restrict__ C,
    const int M, const int N, const int K) {
  __shared__ _Float16 Ah[128][40];
  __shared__ _Float16 Al[128][40];
  __shared__ _Float16 Bh[128][40];  // [n][k] (B^T layout)
  __shared__ _Float16 Bl[128][40];

  const int t = threadIdx.x;
  const int bn = blockIdx.x, bm = blockIdx.y;
  const int lane = t & 63, wv = t >> 6;
  const int wm = (wv >> 1) << 6;  // wave row offset (0/64)
  const int wn = (wv & 1) << 6;   // wave col offset (0/64)
  const int fr = lane & 15;       // frag row (A) / col (B,C)
  const int fg = lane >> 4;       // k-group (inputs), row-group (C)

  f32x4 acc[4][4];
#pragma unroll
  for (int i = 0; i < 4; i++)
#pragma unroll
    for (int j = 0; j < 4; j++) {
      f32x4 z = {0.f, 0.f, 0.f, 0.f};
      acc[i][j] = z;
    }

  // staging assignments
  const int am = t >> 1, ak = (t & 1) << 4;            // A: row, 16-k half
  const int wk0 = (t >> 5) << 2, wn0 = (t & 31) << 2;  // W: 4k x 4n block

  const float* Ag = A + (size_t)(bm * 128 + am) * K + ak;
  const float* Wg = W + (size_t)wk0 * N + (size_t)bn * 128 + wn0;

  for (int kk = 0; kk < K; kk += 32) {
    // ---- stage A: 128 rows x 32 k (16 f32/thread) ----
    {
      const float* ap = Ag + kk;
      const f32x4 a0 = *(const f32x4*)(ap);
      const f32x4 a1 = *(const f32x4*)(ap + 4);
      const f32x4 a2 = *(const f32x4*)(ap + 8);
      const f32x4 a3 = *(const f32x4*)(ap + 12);
      f16x8 h0, l0, h1, l1;
#pragma unroll
      for (int j = 0; j < 4; j++) {
        const _Float16 ha = (_Float16)a0[j];
        h0[j] = ha; l0[j] = (_Float16)(a0[j] - (float)ha);
        const _Float16 hb = (_Float16)a1[j];
        h0[j + 4] = hb; l0[j + 4] = (_Float16)(a1[j] - (float)hb);
        const _Float16 hc = (_Float16)a2[j];
        h1[j] = hc; l1[j] = (_Float16)(a2[j] - (float)hc);
        const _Float16 hd = (_Float16)a3[j];
        h1[j + 4] = hd; l1[j + 4] = (_Float16)(a3[j] - (float)hd);
      }
      *(f16x8*)&Ah[am][ak] = h0;
      *(f16x8*)&Ah[am][ak + 8] = h1;
      *(f16x8*)&Al[am][ak] = l0;
      *(f16x8*)&Al[am][ak + 8] = l1;
    }
    // ---- stage W transposed: 32 k x 128 n (4x4 block/thread) ----
    {
      f32x4 wr[4];
#pragma unroll
      for (int i = 0; i < 4; i++)
        wr[i] = *(const f32x4*)(Wg + (size_t)(kk + i) * N);
#pragma unroll
      for (int j = 0; j < 4; j++) {
        f16x4 ph, pl;
#pragma unroll
        for (int i = 0; i < 4; i++) {
          const float wval = wr[i][j];
          const _Float16 hv = (_Float16)wval;
          ph[i] = hv;
          pl[i] = (_Float16)(wval - (float)hv);
        }
        *(f16x4*)&Bh[wn0 + j][wk0] = ph;
        *(f16x4*)&Bl[wn0 + j][wk0] = pl;
      }
    }
    __syncthreads();

    // ---- MFMA: 4x4 frags x 3 terms ----
    f16x8 ah[4], al[4];
#pragma unroll
    for (int mi = 0; mi < 4; mi++) {
      ah[mi] = *(const f16x8*)&Ah[wm + (mi << 4) + fr][fg << 3];
      al[mi] = *(const f16x8*)&Al[wm + (mi << 4) + fr][fg << 3];
    }
#pragma unroll
    for (int ni = 0; ni < 4; ni++) {
      const f16x8 bh = *(const f16x8*)&Bh[wn + (ni << 4) + fr][fg << 3];
      const f16x8 bl = *(const f16x8*)&Bl[wn + (ni << 4) + fr][fg << 3];
#pragma unroll
      for (int mi = 0; mi < 4; mi++) {
        acc[mi][ni] = __builtin_amdgcn_mfma_f32_16x16x32_f16(ah[mi], bh, acc[mi][ni], 0, 0, 0);
        acc[mi][ni] = __builtin_amdgcn_mfma_f32_16x16x32_f16(al[mi], bh, acc[mi][ni], 0, 0, 0);
        acc[mi][ni] = __builtin_amdgcn_mfma_f32_16x16x32_f16(ah[mi], bl, acc[mi][ni], 0, 0, 0);
      }
    }
    __syncthreads();
  }

  // ---- epilogue: C = acc + bias (+ReLU) ----
  // C/D layout: col = lane&15, row = (lane>>4)*4 + reg  [m89-verified]
#pragma unroll
  for (int ni = 0; ni < 4; ni++) {
    const int col = bn * 128 + wn + (ni << 4) + fr;
    const float bb = bias[col];
#pragma unroll
    for (int mi = 0; mi < 4; mi++) {
      const int row0 = bm * 128 + wm + (mi << 4) + (fg << 2);
#pragma unroll
      for (int r = 0; r < 4; r++) {
        float vv = acc[mi][ni][r] + bb;
        if (RELU) vv = fmaxf(vv, 0.f);
        C[(size_t)(row0 + r) * N + col] = vv;
      }
    }
  }
}

// Two-pass LDS-staged attention. One block per (b, head, 8 query rows), 256 threads.
__global__ void attn_kernel(const float* __restrict__ q, const float* __restrict__ k,
                            const float* __restrict__ v, float* __restrict__ o) {
  const int qb = blockIdx.x, nh = blockIdx.y, b = blockIdx.z;
  const int t = threadIdx.x;
  __shared__ float qs[8][HEADD];
  __shared__ float sc[8][SEQLEN];   // 32 KB: full score rows (exact 2-pass softmax)
  __shared__ float kv[64][65];      // staged K or V tile, +1 pad => bank-friendly
  __shared__ float sinv[8];
  const size_t bbase = (size_t)b * SEQLEN * HDIM + (size_t)nh * HEADD;
  const float* kb = k + bbase;
  const float* vb = v + bbase;
  const int srow = t >> 4;          // stage: base row 0..15
  const int scol = (t & 15) << 2;   // stage: float4 col offset 0..60

  for (int idx = t; idx < 8 * HEADD; idx += 256) {
    const int qq = idx >> 6, d = idx & 63;
    qs[qq][d] = q[bbase + (size_t)(qb * 8 + qq) * HDIM + d];
  }

  // ---- Phase A: scores ----
  const int kk = t & 63, qp = t >> 6;  // thread -> k-col, q-row pair {qp, qp+4}
  for (int kt = 0; kt < 16; kt++) {
    __syncthreads();  // prev tile's reads done (first iter: q-stage done)
#pragma unroll
    for (int i = 0; i < 4; i++) {
      const int r = srow + (i << 4);
      const float4 t4 = *(const float4*)(kb + (size_t)((kt << 6) + r) * HDIM + scol);
      kv[r][scol] = t4.x; kv[r][scol + 1] = t4.y;
      kv[r][scol + 2] = t4.z; kv[r][scol + 3] = t4.w;
    }
    __syncthreads();
    float s0 = 0.f, s1 = 0.f;
#pragma unroll
    for (int d = 0; d < HEADD; d++) {
      const float kvv = kv[kk][d];           // (kk+d)%32 banks: 2-way, free
      s0 += qs[qp][d] * kvv;                 // broadcast (wave-uniform addr)
      s1 += qs[qp + 4][d] * kvv;
    }
    sc[qp][(kt << 6) + kk] = s0 * 0.125f;    // 1/sqrt(64)
    sc[qp + 4][(kt << 6) + kk] = s1 * 0.125f;
  }
  __syncthreads();

  // ---- Phase B: softmax (wave w owns rows w and w+4) ----
  const int w = t >> 6, l = t & 63;
#pragma unroll
  for (int rr = 0; rr < 2; rr++) {
    const int r = w + (rr << 2);
    float m = -1e30f;
#pragma unroll
    for (int i = 0; i < 16; i++) m = fmaxf(m, sc[r][l + (i << 6)]);
#pragma unroll
    for (int off = 32; off > 0; off >>= 1) m = fmaxf(m, __shfl_xor(m, off));
    float s = 0.f;
#pragma unroll
    for (int i = 0; i < 16; i++) {
      const float e = __expf(sc[r][l + (i << 6)] - m);
      sc[r][l + (i << 6)] = e;
      s += e;
    }
#pragma unroll
    for (int off = 32; off > 0; off >>= 1) s += __shfl_xor(s, off);
    if (l == 0) sinv[r] = 1.f / s;
  }

  // ---- Phase C: o = P @ V ----
  // lane owns (q-row qq, dims dd and dd+32): kv[j][dd] conflict-free
  // (32 consecutive banks; wave-halves same addr => broadcast)
  const int dd = t & 31, qq = t >> 5;
  float o0 = 0.f, o1 = 0.f;
  for (int kt = 0; kt < 16; kt++) {
    __syncthreads();  // softmax done / prev tile reads done
#pragma unroll
    for (int i = 0; i < 4; i++) {
      const int r = srow + (i << 4);
      const float4 t4 = *(const float4*)(vb + (size_t)((kt << 6) + r) * HDIM + scol);
      kv[r][scol] = t4.x; kv[r][scol + 1] = t4.y;
      kv[r][scol + 2] = t4.z; kv[r][scol + 3] = t4.w;
    }
    __syncthreads();
#pragma unroll
    for (int j = 0; j < 64; j++) {
      const float p = sc[qq][(kt << 6) + j];  // broadcast within 32-lane group
      o0 += p * kv[j][dd];
      o1 += p * kv[j][dd + 32];
    }
  }
  const float inv = sinv[qq];
  const size_t obase = bbase + (size_t)(qb * 8 + qq) * HDIM + dd;
  o[obase] = o0 * inv;
  o[obase + 32] = o1 * inv;
}

// h = LayerNorm(h + t_in) * g + b   (one block per token, H=1024, 4 elems/thread)
__global__ void ln_kernel(float* __restrict__ h, const float* __restrict__ t_in,
                          const float* __restrict__ g, const float* __restrict__ bta) {
  const int tok = blockIdx.x;
  const int t = threadIdx.x;
  __shared__ float red[8];
  float r[4];
  float s = 0.f;
  const size_t base = (size_t)tok * HDIM;
#pragma unroll
  for (int i = 0; i < 4; i++) {
    const int d = t + (i << 8);
    r[i] = h[base + d] + t_in[base + d];
    s += r[i];
  }
#pragma unroll
  for (int off = 32; off > 0; off >>= 1) s += __shfl_xor(s, off);
  if ((t & 63) == 0) red[t >> 6] = s;
  __syncthreads();
  const float mean = (red[0] + red[1] + red[2] + red[3]) * (1.f / HDIM);
  float vs = 0.f;
#pragma unroll
  for (int i = 0; i < 4; i++) {
    const float dv = r[i] - mean;
    vs += dv * dv;
  }
#pragma unroll
  for (int off = 32; off > 0; off >>= 1) vs += __shfl_xor(vs, off);
  if ((t & 63) == 0) red[4 + (t >> 6)] = vs;
  __syncthreads();
  const float var = (red[4] + red[5] + red[6] + red[7]) * (1.f / HDIM);
  const float inv = 1.f / sqrtf(var + 1e-5f);
#pragma unroll
  for (int i = 0; i < 4; i++) {
    const int d = t + (i << 8);
    h[base + d] = (r[i] - mean) * inv * g[d] + bta[d];
  }
}

extern "C" void kernel_launch(void* const* d_in, const int* in_sizes, int n_in,
                              void* d_out, int out_size, void* d_ws, size_t ws_size,
                              hipStream_t stream) {
  const int* x = (const int*)d_in[0];
  const float* emb = (const float*)d_in[1];
  const float* Wq = (const float*)d_in[2];
  const float* bq = (const float*)d_in[3];
  const float* Wk = (const float*)d_in[4];
  const float* bk = (const float*)d_in[5];
  const float* Wv = (const float*)d_in[6];
  const float* bv = (const float*)d_in[7];
  const float* Wo = (const float*)d_in[8];
  const float* bo = (const float*)d_in[9];
  const float* ln1g = (const float*)d_in[10];
  const float* ln1b = (const float*)d_in[11];
  const float* W1 = (const float*)d_in[12];
  const float* b1 = (const float*)d_in[13];
  const float* W2 = (const float*)d_in[14];
  const float* b2 = (const float*)d_in[15];
  const float* ln2g = (const float*)d_in[16];
  const float* ln2b = (const float*)d_in[17];
  const float* fcw = (const float*)d_in[18];
  const float* fcb = (const float*)d_in[19];

  float* h = (float*)d_ws;
  const size_t TH = (size_t)NTOK * HDIM;  // 2M floats
  float* qb = h + TH;
  float* kb = qb + TH;
  float* vb = kb + TH;
  float* ob = vb + TH;
  float* tb = ob + TH;
  float* ffb = tb + TH;  // NTOK * FFDIM floats

  embed_kernel<<<NTOK, 256, 0, stream>>>(x, emb, h);

  const dim3 gHH(HDIM / 128, NTOK / 128);
  const dim3 gHF(FFDIM / 128, NTOK / 128);
  const dim3 gHV(VOCAB / 128, NTOK / 128);
  for (int l = 0; l < NLAYERS; l++) {
    const size_t wHH = (size_t)l * HDIM * HDIM;
    gemm_mfma<false><<<gHH, 256, 0, stream>>>(h, Wq + wHH, bq + l * HDIM, qb, NTOK, HDIM, HDIM);
    gemm_mfma<false><<<gHH, 256, 0, stream>>>(h, Wk + wHH, bk + l * HDIM, kb, NTOK, HDIM, HDIM);
    gemm_mfma<false><<<gHH, 256, 0, stream>>>(h, Wv + wHH, bv + l * HDIM, vb, NTOK, HDIM, HDIM);
    attn_kernel<<<dim3(SEQLEN / 8, NHEAD, NBATCH), 256, 0, stream>>>(qb, kb, vb, ob);
    gemm_mfma<false><<<gHH, 256, 0, stream>>>(ob, Wo + wHH, bo + l * HDIM, tb, NTOK, HDIM, HDIM);
    ln_kernel<<<NTOK, 256, 0, stream>>>(h, tb, ln1g + l * HDIM, ln1b + l * HDIM);
    gemm_mfma<true><<<gHF, 256, 0, stream>>>(h, W1 + (size_t)l * HDIM * FFDIM, b1 + l * FFDIM,
                                             ffb, NTOK, FFDIM, HDIM);
    gemm_mfma<false><<<gHH, 256, 0, stream>>>(ffb, W2 + (size_t)l * FFDIM * HDIM, b2 + l * HDIM,
                                              tb, NTOK, HDIM, FFDIM);
    ln_kernel<<<NTOK, 256, 0, stream>>>(h, tb, ln2g + l * HDIM, ln2b + l * HDIM);
  }
  gemm_mfma<false><<<gHV, 256, 0, stream>>>(h, fcw, fcb, (float*)d_out, NTOK, VOCAB, HDIM);
}